// Round 11
// baseline (269.853 us; speedup 1.0000x reference)
//
#include <hip/hip_runtime.h>
#include <math.h>

#define NN 50000
#define NE 800000
#define SLOPE 0.2f
#define NEGX (-1e30f)
#define CH 4096
#define HB 128

typedef _Float16 h8 __attribute__((ext_vector_type(8)));
typedef _Float16 h2 __attribute__((ext_vector_type(2)));
typedef float f8 __attribute__((ext_vector_type(8)));
typedef float v4f __attribute__((ext_vector_type(4)));

__device__ __forceinline__ h8 hzero(){ h8 z = {0,0,0,0,0,0,0,0}; return z; }
__device__ __forceinline__ f8 fzero(){ f8 z = {0,0,0,0,0,0,0,0}; return z; }

// ---------------- fused weight pack (fp16 fragment order) + edge histogram ----
__device__ __forceinline__ void pack_one(const float* __restrict__ W,
                                         _Float16* __restrict__ Wp,
                                         int DO, int K, int NT, int t){
  int KC = K >> 5;
  if (t >= NT * KC * 64) return;
  int lane = t & 63;
  int rest = t >> 6;
  int c  = rest % KC;
  int nt = rest / KC;
  int col = nt * 16 + (lane & 15);
  int k0  = c * 32 + ((lane >> 4) << 3);
  _Float16 o[8];
#pragma unroll
  for (int j = 0; j < 8; j++){
    float v = (col < DO) ? W[(k0 + j) * DO + col] : 0.f;
    o[j] = (_Float16)v;
  }
  *(ulonglong2*)(Wp + (size_t)t * 8) = *(ulonglong2*)o;
}

// packs weights; histograms edges by dst bucket (LDS atomics only -> gbp
// partials, HB=128 hist blocks for latency hiding); zeroes cursor arrays;
// writes row_ptr[NN]=NE.
__global__ __launch_bounds__(256) void k_pack_hist(
    const float* W1l, const float* W1r, const float* W2l,
    const float* W2r, const float* W3l, const float* W3r,
    _Float16* p1l, _Float16* p1r, _Float16* p2l,
    _Float16* p2r, _Float16* p3l, _Float16* p3r,
    const int* __restrict__ ei, int* __restrict__ gbp,
    int* __restrict__ bcur, int* __restrict__ row_ptr){
  __shared__ int h[256];
  int b = blockIdx.x, t = threadIdx.x;
  if (b < 44){
    if      (b < 16) pack_one(W1l, p1l, 128, 256, 8, (b     ) * 256 + t);
    else if (b < 32) pack_one(W1r, p1r, 128, 256, 8, (b - 16) * 256 + t);
    else if (b < 36) pack_one(W2l, p2l,  64, 128, 4, (b - 32) * 256 + t);
    else if (b < 40) pack_one(W2r, p2r,  64, 128, 4, (b - 36) * 256 + t);
    else if (b < 42) pack_one(W3l, p3l,  40,  64, 3, (b - 40) * 256 + t);
    else             pack_one(W3r, p3r,  40,  64, 3, (b - 42) * 256 + t);
  } else {
    int hb = b - 44;                 // 0..HB-1, each owns NE/HB = 6250 edges
    if (hb == 0 && t == 0) row_ptr[NN] = NE;
    if (hb == 1){ bcur[t] = 0; bcur[256 + t] = 0; bcur[512 + t] = 0; }
    h[t] = 0;
    __syncthreads();
    int e0 = hb * (NE / HB);
    for (int i = t; i < NE / HB; i += 256)
      atomicAdd(&h[ei[NE + e0 + i] >> 8], 1);
    __syncthreads();
    gbp[hb * 256 + t] = h[t];        // non-atomic partials
  }
}

// ---------------- Direct-load MFMA dual GEMM body (layer 1) ------------------
// B direct from L2 (rounds 9/10 proved staging/occupancy don't matter).
// NEW: C written via register accumulation of all 8 nt-tiles -> LDS tile
// (stride 136 halves, ~2-way bank alias = free) -> cooperative 256B-row
// coalesced stores. Replaces 64 scalar 2B stores/thread (16x 32B segments
// per wave-store) with 16B/thread fully-coalesced rows.
__device__ __forceinline__ void gemm_body(
    int bb, _Float16* __restrict__ cs,        // 64*136 halves (17.4KB LDS)
    const float* __restrict__ X,
    const _Float16* __restrict__ Wpl, const float* __restrict__ bl,
    const _Float16* __restrict__ Wpr, const float* __restrict__ br,
    _Float16* __restrict__ Yl, _Float16* __restrict__ Yr)
{
  constexpr int K = 256, DO = 128;
  constexpr int KC = K / 32;
  constexpr int NT = DO / 16;
  constexpr int LCS = DO + 8;              // padded LDS row stride (halves)
  int tid  = threadIdx.x;
  int lane = tid & 63;
  int wv   = tid >> 6;
  int row0 = (bb * 4 + wv) * 16;           // m-tile base
  int arow = lane & 15;
  int koff = lane >> 4;
  int lrow = row0 + arow;
  int crow = (lrow < NN) ? lrow : 0;       // clamp loads; stores masked

  h8 afrag[KC];
  const float* Xr = X + (size_t)crow * K + koff * 8;
#pragma unroll
  for (int c = 0; c < KC; c++){
    float4 v0 = *reinterpret_cast<const float4*>(Xr + c * 32);
    float4 v1 = *reinterpret_cast<const float4*>(Xr + c * 32 + 4);
    h8 a;
    a[0]=(_Float16)v0.x; a[1]=(_Float16)v0.y; a[2]=(_Float16)v0.z; a[3]=(_Float16)v0.w;
    a[4]=(_Float16)v1.x; a[5]=(_Float16)v1.y; a[6]=(_Float16)v1.z; a[7]=(_Float16)v1.w;
    afrag[c] = a;
  }

  int rowL = wv * 16 + koff * 4;           // row within block C-tile

#pragma unroll
  for (int side = 0; side < 2; side++){
    const _Float16* Wp = side ? Wpr : Wpl;
    const float* bias = side ? br : bl;
    _Float16* Y = side ? Yr : Yl;
    v4f acc[NT];
#pragma unroll
    for (int nt = 0; nt < NT; nt++){
      v4f a = {0.f, 0.f, 0.f, 0.f};
#pragma unroll
      for (int c = 0; c < KC; c++){
        h8 b = *reinterpret_cast<const h8*>(Wp + (size_t)((nt * KC + c) * 64 + lane) * 8);
        a = __builtin_amdgcn_mfma_f32_16x16x32_f16(afrag[c], b, a, 0, 0, 0);
      }
      acc[nt] = a;
    }
    if (side) __syncthreads();             // prev side's LDS readers done
    // C fragment -> LDS (+bias)
#pragma unroll
    for (int nt = 0; nt < NT; nt++){
      int col = nt * 16 + arow;
      float bv = bias[col];
#pragma unroll
      for (int r = 0; r < 4; r++)
        cs[(rowL + r) * LCS + col] = (_Float16)(acc[nt][r] + bv);
    }
    __syncthreads();
    // cooperative coalesced store: 64 rows x 256B (16B per thread, 4 passes)
#pragma unroll
    for (int pass = 0; pass < 4; pass++){
      int idx = pass * 256 + tid;          // 0..1023
      int row = idx >> 4, ch = idx & 15;
      int orow = bb * 64 + row;
      if (orow < NN){
        ulonglong2 v = *reinterpret_cast<const ulonglong2*>(cs + row * LCS + ch * 8);
        *reinterpret_cast<ulonglong2*>(Y + (size_t)orow * DO + ch * 8) = v;
      }
    }
  }
}

#define GB ((NN + 63) / 64)             // 782 gemm1 blocks
#define SB ((NE + CH - 1) / CH)         // 196 scatter blocks

// ---------------- Fused dispatch: gemm1 (first, long pole) || bscatter -------
// blocks 0..GB-1     : layer-1 dual GEMM (coalesced C via LDS)
// blocks GB..GB+SB-1 : edge scatter into dst buckets (self-scans gbp for
//                      bases; first scatter block publishes base[] for k_bcsr)
__global__ __launch_bounds__(256, 4) void k_fused2(
    const int* __restrict__ ei, const int* __restrict__ gbp,
    int* __restrict__ bcur, int* __restrict__ base,
    unsigned* __restrict__ pk_out,
    const float* __restrict__ X,
    const _Float16* __restrict__ Wpl, const float* __restrict__ bl,
    const _Float16* __restrict__ Wpr, const float* __restrict__ br,
    _Float16* __restrict__ Yl, _Float16* __restrict__ Yr)
{
  __shared__ __align__(16) unsigned char smem_raw[(CH + 512) * 4];  // 18.4KB
  int b = blockIdx.x, t = threadIdx.x;
  if (b < GB){
    gemm_body(b, (_Float16*)smem_raw, X, Wpl, bl, Wpr, br, Yl, Yr);
  } else {
    int sb = b - GB;
    unsigned* pk = (unsigned*)smem_raw;
    int* h = (int*)pk + CH;
    int* s = h + 256;
    // self-scan of gbp -> bucket base (exclusive)
    int v = 0;
#pragma unroll 8
    for (int i = 0; i < HB; i++) v += gbp[i * 256 + t];
    s[t] = v; __syncthreads();
    for (int off = 1; off < 256; off <<= 1){
      int a = (t >= off) ? s[t - off] : 0;
      __syncthreads(); s[t] += a; __syncthreads();
    }
    int ex = s[t] - v;
    if (sb == 0){
      base[t] = ex;
      if (t == 255) base[256] = NE;
    }
    h[t] = 0;
    __syncthreads();
    int e0 = sb * CH;
    int n = NE - e0; if (n > CH) n = CH;
    for (int i = t; i < n; i += 256){
      int e = e0 + i;
      int sN = ei[e], d = ei[NE + e];
      pk[i] = (unsigned)sN | ((unsigned)(d & 255) << 16) | ((unsigned)(d >> 8) << 24);
      atomicAdd(&h[d >> 8], 1);
    }
    __syncthreads();
    int c = h[t];
    if (c) h[t] = ex + atomicAdd(&bcur[t], c);
    __syncthreads();
    for (int i = t; i < n; i += 256){
      unsigned u = pk[i];
      int pos = atomicAdd(&h[u >> 24], 1);
      pk_out[pos] = u;
    }
  }
}

// per-bucket CSR finalize + per-node degree histogram (for degree sort)
__global__ __launch_bounds__(256) void k_bcsr(const unsigned* __restrict__ pk,
                                              const int* __restrict__ base,
                                              int* __restrict__ row_ptr,
                                              int* __restrict__ csr_src,
                                              int* __restrict__ dcnt){
  __shared__ int h[256], s[256];
  int t = threadIdx.x;
  int b = blockIdx.x;
  int lo = base[b], hi = base[b + 1];
  h[t] = 0;
  __syncthreads();
  for (int i = lo + t; i < hi; i += 256)
    atomicAdd(&h[(pk[i] >> 16) & 255], 1);
  __syncthreads();
  int v = h[t];
  s[t] = v; __syncthreads();
  for (int off = 1; off < 256; off <<= 1){
    int a = (t >= off) ? s[t - off] : 0;
    __syncthreads(); s[t] += a; __syncthreads();
  }
  int ex = lo + s[t] - v;
  int node = b * 256 + t;
  if (node < NN) row_ptr[node] = ex;
  h[t] = ex;
  // ---- degree histogram (reuse s[] as bins) ----
  s[t] = 0;
  __syncthreads();
  if (node < NN) atomicAdd(&s[v < 255 ? v : 255], 1);
  __syncthreads();
  if (s[t]) atomicAdd(&dcnt[t], s[t]);
  // ---- scatter csr ----
  for (int i = lo + t; i < hi; i += 256){
    unsigned u = pk[i];
    int pos = atomicAdd(&h[(u >> 16) & 255], 1);
    csr_src[pos] = (int)(u & 0xFFFFu);
  }
}

// degree-sort scatter; does its own (redundant per-block) scan of dcnt.
__global__ __launch_bounds__(256) void k_dscatter(const int* __restrict__ row_ptr,
                                                  const int* __restrict__ dcnt,
                                                  int* __restrict__ dcur,
                                                  int* __restrict__ perm){
  __shared__ int lh[256], sc[256];
  int t = threadIdx.x;
  int node = blockIdx.x * 256 + t;
  lh[t] = 0;
  int dv = dcnt[t];
  __syncthreads();
  int bin = -1;
  if (node < NN){
    int deg = row_ptr[node + 1] - row_ptr[node];
    bin = deg < 255 ? deg : 255;
    atomicAdd(&lh[bin], 1);
  }
  sc[t] = dv;
  __syncthreads();
  for (int off = 1; off < 256; off <<= 1){
    int a = (t >= off) ? sc[t - off] : 0;
    __syncthreads(); sc[t] += a; __syncthreads();
  }
  int gbase = sc[t] - dv;             // exclusive global base of bin t
  int c = lh[t];
  int bp = c ? (gbase + atomicAdd(&dcur[t], c)) : 0;
  __syncthreads();
  lh[t] = bp;
  __syncthreads();
  if (node < NN){
    int pos = atomicAdd(&lh[bin], 1);
    perm[pos] = node;
  }
}

// ---------------- agg helpers ----------------
// DPP-based cross-lane reduction: pure VALU (no ds_swizzle latency chain).
template<int CTRL>
__device__ __forceinline__ float dppmv(float v){
  int x = __builtin_amdgcn_update_dpp(0, __float_as_int(v), CTRL, 0xF, 0xF, true);
  return __int_as_float(x);
}

template<int LPG>
__device__ __forceinline__ float gsum(float v){
  v += dppmv<177>(v);                 // quad_perm [1,0,3,2]  (xor1)
  v += dppmv<78>(v);                  // quad_perm [2,3,0,1]  (xor2)
  if (LPG >= 8)  v += dppmv<0x141>(v);  // row_half_mirror (cross-quad)
  if (LPG == 16) v += dppmv<0x140>(v);  // row_mirror (cross-half)
  return v;
}
template<int LPG>
__device__ __forceinline__ void gsum2(float& a, float& b){
  a = gsum<LPG>(a);
  b = gsum<LPG>(b);
}
template<int LPG>
__device__ __forceinline__ void gsum4(float& a, float& b, float& c, float& d){
  a = gsum<LPG>(a);
  b = gsum<LPG>(b);
  c = gsum<LPG>(c);
  d = gsum<LPG>(d);
}
template<int LPG>
__device__ __forceinline__ float gmax(float v){
  v = fmaxf(v, dppmv<177>(v));
  v = fmaxf(v, dppmv<78>(v));
  if (LPG >= 8)  v = fmaxf(v, dppmv<0x141>(v));
  if (LPG == 16) v = fmaxf(v, dppmv<0x140>(v));
  return v;
}

__device__ __forceinline__ float edge_logit(h8 x, h8 xrv, h8 attv){
  h8 t = x + xrv;
  h8 l = __builtin_elementwise_max(t, t * (_Float16)SLOPE);
  const h2* lp = (const h2*)&l;
  const h2* ap = (const h2*)&attv;
  float d = __builtin_amdgcn_fdot2(lp[0], ap[0], 0.f, false);
  d = __builtin_amdgcn_fdot2(lp[1], ap[1], d, false);
  d = __builtin_amdgcn_fdot2(lp[2], ap[2], d, false);
  d = __builtin_amdgcn_fdot2(lp[3], ap[3], d, false);
  return d;
}

// weighted accumulate, element-wise fp16->f32 mixed FMA (v_fma_mix_f32).
__device__ __forceinline__ void fmix(f8& acc, h8 x, float w){
#pragma unroll
  for (int j = 0; j < 8; j++) acc[j] = fmaf((float)x[j], w, acc[j]);
}

// ---------------- Fused agg(layer l) + gemm(layer l+1) ----------------
template<int DO, int LPG, int DO2>
__global__ __launch_bounds__(256) void agg_gemm(
    const _Float16* __restrict__ xl, const _Float16* __restrict__ xr,
    const int* __restrict__ csr_src, const int* __restrict__ row_ptr,
    const int* __restrict__ perm,
    const float* __restrict__ att, const float* __restrict__ bias,
    const _Float16* __restrict__ Wpl2, const float* __restrict__ bl2,
    const _Float16* __restrict__ Wpr2, const float* __restrict__ br2,
    _Float16* __restrict__ Yl, _Float16* __restrict__ Yr)
{
  constexpr int G = 64 / LPG;
  constexpr int NPB = 4 * G;            // nodes per block
  constexpr int LK = DO + 8;            // padded LDS row stride (halves)
  constexpr int KC2 = DO / 32;
  constexpr int NT2 = (DO2 + 15) / 16;
  constexpr int MT = NPB / 16;          // m-tiles per block (1 or 2)
  __shared__ _Float16 hs[NPB * LK];
  __shared__ int nodeOf[NPB];

  int tid  = threadIdx.x;
  int lane = tid & 63;
  int wid  = tid >> 6;

  unsigned seg = (unsigned)(blockIdx.x * 1021u) % gridDim.x;  // coprime interleave
  if (tid < NPB){
    int idx = seg * NPB + tid;
    nodeOf[tid] = (idx < NN) ? perm[idx] : NN;
  }
  __syncthreads();

  int g = lane / LPG, p = lane % LPG;
  int nodeLocal = wid * G + g;
  int node = nodeOf[nodeLocal];
  int cbase = p * 8;
  bool nvalid = node < NN;
  int nodeC = nvalid ? node : 0;

  // ---- agg phase ----
  h8 attv, xrv, xlv;
  {
    float4 a0 = *reinterpret_cast<const float4*>(att + cbase);
    float4 a1 = *reinterpret_cast<const float4*>(att + cbase + 4);
    attv[0]=(_Float16)a0.x; attv[1]=(_Float16)a0.y; attv[2]=(_Float16)a0.z; attv[3]=(_Float16)a0.w;
    attv[4]=(_Float16)a1.x; attv[5]=(_Float16)a1.y; attv[6]=(_Float16)a1.z; attv[7]=(_Float16)a1.w;
    xrv = *reinterpret_cast<const h8*>(xr + nodeC * DO + cbase);
    xlv = *reinterpret_cast<const h8*>(xl + nodeC * DO + cbase);
  }
  float s = gsum<LPG>(edge_logit(xlv, xrv, attv));
  float wS = __expf(s);
  float denA = wS, denB = 0.f;
  f8 accA = fzero(), accB = fzero();
  fmix(accA, xlv, wS);

  int e0 = row_ptr[nodeC];
  int e1 = nvalid ? row_ptr[nodeC + 1] : e0;
  int e = e0;
  for (; e + 3 < e1; e += 4){
    int s0 = csr_src[e],     s1 = csr_src[e + 1];
    int s2 = csr_src[e + 2], s3 = csr_src[e + 3];
    h8 x0 = *reinterpret_cast<const h8*>(xl + s0 * DO + cbase);
    h8 x1 = *reinterpret_cast<const h8*>(xl + s1 * DO + cbase);
    h8 x2 = *reinterpret_cast<const h8*>(xl + s2 * DO + cbase);
    h8 x3 = *reinterpret_cast<const h8*>(xl + s3 * DO + cbase);
    float p0 = edge_logit(x0, xrv, attv);
    float p1 = edge_logit(x1, xrv, attv);
    float p2 = edge_logit(x2, xrv, attv);
    float p3 = edge_logit(x3, xrv, attv);
    gsum4<LPG>(p0, p1, p2, p3);
    float w0 = __expf(p0), w1 = __expf(p1);
    float w2 = __expf(p2), w3 = __expf(p3);
    denA += w0 + w2; denB += w1 + w3;
    fmix(accA, x0, w0);
    fmix(accB, x1, w1);
    fmix(accA, x2, w2);
    fmix(accB, x3, w3);
  }
  for (; e + 1 < e1; e += 2){
    int sA = csr_src[e], sB = csr_src[e + 1];
    h8 xA = *reinterpret_cast<const h8*>(xl + sA * DO + cbase);
    h8 xB = *reinterpret_cast<const h8*>(xl + sB * DO + cbase);
    float pA = edge_logit(xA, xrv, attv);
    float pB = edge_logit(xB, xrv, attv);
    gsum2<LPG>(pA, pB);
    float wA = __expf(pA), wB = __expf(pB);
    denA += wA; denB += wB;
    fmix(accA, xA, wA);
    fmix(accB, xB, wB);
  }
  if (e < e1){
    int sA = csr_src[e];
    h8 xA = *reinterpret_cast<const h8*>(xl + sA * DO + cbase);
    float pA = gsum<LPG>(edge_logit(xA, xrv, attv));
    float w = __expf(pA);
    denA += w;
    fmix(accA, xA, w);
  }

  {
    float inv = 1.0f / (denA + denB);
    f8 sum = (accA + accB) * inv;
    float4 b0 = *reinterpret_cast<const float4*>(bias + cbase);
    float4 b1 = *reinterpret_cast<const float4*>(bias + cbase + 4);
    f8 bv = {b0.x, b0.y, b0.z, b0.w, b1.x, b1.y, b1.z, b1.w};
    sum += bv;
    sum = __builtin_elementwise_max(sum, fzero());
    *reinterpret_cast<h8*>(&hs[nodeLocal * LK + cbase]) = __builtin_convertvector(sum, h8);
  }
  __syncthreads();

  // ---- gemm phase: next layer, A from LDS, B from packed W (L2) ----
  int arow = lane & 15;
  int koff = lane >> 4;
  int mt = (MT == 1) ? 0 : (wid >> 1);
  h8 afrag[KC2];
#pragma unroll
  for (int c = 0; c < KC2; c++)
    afrag[c] = *reinterpret_cast<const h8*>(&hs[(mt * 16 + arow) * LK + koff * 8 + c * 32]);

  int side = wid & 1;
  const _Float16* Wp = side ? Wpr2 : Wpl2;
  const float* bias2 = side ? br2 : bl2;
  _Float16* Y = side ? Yr : Yl;
  int nt_begin = (MT == 1) ? (wid >> 1) * (NT2 / 2) : 0;
  int nt_end   = (MT == 1) ? nt_begin + NT2 / 2 : NT2;
  for (int nt = nt_begin; nt < nt_end; nt++){
    v4f acc = {0.f, 0.f, 0.f, 0.f};
#pragma unroll
    for (int c = 0; c < KC2; c++){
      h8 b = *reinterpret_cast<const h8*>(Wp + (size_t)((nt * KC2 + c) * 64 + lane) * 8);
      acc = __builtin_amdgcn_mfma_f32_16x16x32_f16(afrag[c], b, acc, 0, 0, 0);
    }
    int col = nt * 16 + arow;
    if (col < DO2){
      float bv = bias2[col];
      int lrbase = mt * 16 + koff * 4;   // C/D: row = (lane>>4)*4 + reg
#pragma unroll
      for (int r = 0; r < 4; r++){
        int orow = nodeOf[lrbase + r];
        if (orow < NN) Y[(size_t)orow * DO2 + col] = (_Float16)(acc[r] + bv);
      }
    }
  }
}

// ---------------- Final GATv2 aggregate + bias + log_softmax ----------------
template<int DO, int LPG>
__global__ __launch_bounds__(256) void gat_agg_out(
    const _Float16* __restrict__ xl, const _Float16* __restrict__ xr,
    const int* __restrict__ csr_src, const int* __restrict__ row_ptr,
    const int* __restrict__ perm,
    const float* __restrict__ att, const float* __restrict__ bias,
    float* __restrict__ out)
{
  constexpr int G = 64 / LPG;
  constexpr int NPB = 4 * G;
  __shared__ int nodeOf[NPB];
  int tid  = threadIdx.x;
  int lane = tid & 63;
  int wid  = tid >> 6;

  unsigned seg = (unsigned)(blockIdx.x * 1021u) % gridDim.x;
  if (tid < NPB){
    int idx = seg * NPB + tid;
    nodeOf[tid] = (idx < NN) ? perm[idx] : NN;
  }
  __syncthreads();

  int g = lane / LPG;
  int p = lane % LPG;
  int node = nodeOf[wid * G + g];
  bool nvalid = node < NN;
  int nodeC = nvalid ? node : 0;
  int cbase = p * 8;
  bool ok = (cbase < DO);

  h8 attv = hzero(), xrv = hzero(), xlv = hzero();
  if (ok){
    float4 a0 = *reinterpret_cast<const float4*>(att + cbase);
    float4 a1 = *reinterpret_cast<const float4*>(att + cbase + 4);
    attv[0]=(_Float16)a0.x; attv[1]=(_Float16)a0.y; attv[2]=(_Float16)a0.z; attv[3]=(_Float16)a0.w;
    attv[4]=(_Float16)a1.x; attv[5]=(_Float16)a1.y; attv[6]=(_Float16)a1.z; attv[7]=(_Float16)a1.w;
    xrv = *reinterpret_cast<const h8*>(xr + nodeC * DO + cbase);
    xlv = *reinterpret_cast<const h8*>(xl + nodeC * DO + cbase);
  }

  float s = gsum<LPG>(edge_logit(xlv, xrv, attv));
  float wS = __expf(s);
  float denA = wS, denB = 0.f;
  f8 accA = fzero(), accB = fzero();
  fmix(accA, xlv, wS);

  int e0 = row_ptr[nodeC];
  int e1 = nvalid ? row_ptr[nodeC + 1] : e0;
  int e = e0;
  for (; e + 3 < e1; e += 4){
    int s0 = csr_src[e],     s1 = csr_src[e + 1];
    int s2 = csr_src[e + 2], s3 = csr_src[e + 3];
    h8 x0 = ok ? *reinterpret_cast<const h8*>(xl + s0 * DO + cbase) : hzero();
    h8 x1 = ok ? *reinterpret_cast<const h8*>(xl + s1 * DO + cbase) : hzero();
    h8 x2 = ok ? *reinterpret_cast<const h8*>(xl + s2 * DO + cbase) : hzero();
    h8 x3 = ok ? *reinterpret_cast<const h8*>(xl + s3 * DO + cbase) : hzero();
    float p0 = edge_logit(x0, xrv, attv);
    float p1 = edge_logit(x1, xrv, attv);
    float p2 = edge_logit(x2, xrv, attv);
    float p3 = edge_logit(x3, xrv, attv);
    gsum4<LPG>(p0, p1, p2, p3);
    float w0 = __expf(p0), w1 = __expf(p1);
    float w2 = __expf(p2), w3 = __expf(p3);
    denA += w0 + w2; denB += w1 + w3;
    fmix(accA, x0, w0);
    fmix(accB, x1, w1);
    fmix(accA, x2, w2);
    fmix(accB, x3, w3);
  }
  for (; e + 1 < e1; e += 2){
    int sA = csr_src[e], sB = csr_src[e + 1];
    h8 xA = ok ? *reinterpret_cast<const h8*>(xl + sA * DO + cbase) : hzero();
    h8 xB = ok ? *reinterpret_cast<const h8*>(xl + sB * DO + cbase) : hzero();
    float pA = edge_logit(xA, xrv, attv);
    float pB = edge_logit(xB, xrv, attv);
    gsum2<LPG>(pA, pB);
    float wA = __expf(pA), wB = __expf(pB);
    denA += wA; denB += wB;
    fmix(accA, xA, wA);
    fmix(accB, xB, wB);
  }
  if (e < e1){
    int sA = csr_src[e];
    h8 xA = ok ? *reinterpret_cast<const h8*>(xl + sA * DO + cbase) : hzero();
    float pA = gsum<LPG>(edge_logit(xA, xrv, attv));
    float w = __expf(pA);
    denA += w;
    fmix(accA, xA, w);
  }

  float inv = 1.0f / (denA + denB);
  f8 sumv = (accA + accB) * inv;
  float v[8]; float lmax = NEGX;
#pragma unroll
  for (int j = 0; j < 8; j++){
    v[j] = ok ? (sumv[j] + bias[cbase + j]) : NEGX;
    lmax = fmaxf(lmax, v[j]);
  }
  lmax = gmax<LPG>(lmax);
  float lsum = 0.f;
#pragma unroll
  for (int j = 0; j < 8; j++) lsum += __expf(v[j] - lmax);   // idle lanes: exp(NEGX)=0
  lsum = gsum<LPG>(lsum);
  if (ok && nvalid){
    float lg = lmax + __logf(lsum);
    float* op = (float*)out + node * DO + cbase;
    float4 o0, o1;
    o0.x = v[0] - lg; o0.y = v[1] - lg; o0.z = v[2] - lg; o0.w = v[3] - lg;
    o1.x = v[4] - lg; o1.y = v[5] - lg; o1.z = v[6] - lg; o1.w = v[7] - lg;
    *reinterpret_cast<float4*>(op) = o0;
    *reinterpret_cast<float4*>(op + 4) = o1;
  }
}

extern "C" void kernel_launch(void* const* d_in, const int* in_sizes, int n_in,
                              void* d_out, int out_size, void* d_ws, size_t ws_size,
                              hipStream_t stream) {
  const float* x   = (const float*)d_in[0];
  const int*   ei  = (const int*)d_in[1];
  const float* W1l = (const float*)d_in[2];  const float* W1r = (const float*)d_in[3];
  const float* b1l = (const float*)d_in[4];  const float* b1r = (const float*)d_in[5];
  const float* a1  = (const float*)d_in[6];  const float* c1  = (const float*)d_in[7];
  const float* W2l = (const float*)d_in[8];  const float* W2r = (const float*)d_in[9];
  const float* b2l = (const float*)d_in[10]; const float* b2r = (const float*)d_in[11];
  const float* a2  = (const float*)d_in[12]; const float* c2  = (const float*)d_in[13];
  const float* W3l = (const float*)d_in[14]; const float* W3r = (const float*)d_in[15];
  const float* b3l = (const float*)d_in[16]; const float* b3r = (const float*)d_in[17];
  const float* a3  = (const float*)d_in[18]; const float* c3  = (const float*)d_in[19];
  float* outp = (float*)d_out;

  // workspace layout (16B-aligned segments)
  _Float16* xl1 = (_Float16*)d_ws;        // 50000*128
  _Float16* xr1 = xl1 + 6400000;
  _Float16* xl2 = xr1 + 6400000;          // 50000*64
  _Float16* xr2 = xl2 + 3200000;
  _Float16* xl3 = xr2 + 3200000;          // 50000*40
  _Float16* xr3 = xl3 + 2000000;
  _Float16* wp1l = xr3 + 2000000;         // packed weights (fp16)
  _Float16* wp1r = wp1l + 32768;
  _Float16* wp2l = wp1r + 32768;
  _Float16* wp2r = wp2l + 8192;
  _Float16* wp3l = wp2r + 8192;
  _Float16* wp3r = wp3l + 3072;
  unsigned* pk   = (unsigned*)(wp3r + 3072);   // 800000
  int* csr_src   = (int*)(pk + NE);            // 800000
  int* row_ptr   = csr_src + NE;               // 50001
  int* gbp       = row_ptr + 50001;            // HB*256 partial hist
  int* base      = gbp + HB * 256;             // 257
  // cursor block (zeroed by k_pack_hist, contiguous): bcur(256) dcnt(256) dcur(256)
  int* bcur      = base + 257;
  int* dcnt      = bcur + 256;
  int* dcur      = dcnt + 256;
  int* perm      = dcur + 256;                 // 50000 degree-sorted node ids

  const int FB1 = (NN + 15) / 16;         // fused agg1+gemm2: 16 nodes/block
  const int FB2 = (NN + 31) / 32;         // fused agg2+gemm3: 32 nodes/block
  const int AB3 = (NN + 31) / 32;         // agg3: 32 nodes/block (LPG=8)
  const int F2  = GB + SB;                // fused gemm+scatter grid (978)

  // pack weights + bucket histogram + cursor zeroing + row_ptr[NN]
  k_pack_hist<<<44 + HB, 256, 0, stream>>>(W1l, W1r, W2l, W2r, W3l, W3r,
                                           wp1l, wp1r, wp2l, wp2r, wp3l, wp3r,
                                           ei, gbp, bcur, row_ptr);

  // fused: layer-1 GEMM (coalesced C) || edge scatter (self-scan, publishes base)
  k_fused2<<<F2, 256, 0, stream>>>(ei, gbp, bcur, base, pk,
                                   x, wp1l, b1l, wp1r, b1r, xl1, xr1);

  // CSR finalize + degree histogram
  k_bcsr<<<196, 256, 0, stream>>>(pk, base, row_ptr, csr_src, dcnt);

  // degree-sort perm
  k_dscatter<<<196, 256, 0, stream>>>(row_ptr, dcnt, dcur, perm);

  // fused: agg layer1 (relu) + gemm layer2 -> xl2, xr2
  agg_gemm<128,16,64><<<FB1, 256, 0, stream>>>(xl1, xr1, csr_src, row_ptr, perm,
                                               a1, c1, wp2l, b2l, wp2r, b2r, xl2, xr2);

  // fused: agg layer2 (relu) + gemm layer3 -> xl3, xr3
  agg_gemm<64,8,40><<<FB2, 256, 0, stream>>>(xl2, xr2, csr_src, row_ptr, perm,
                                             a2, c2, wp3l, b3l, wp3r, b3r, xl3, xr3);

  // final: agg layer3 + bias + log_softmax -> out
  gat_agg_out<40,8><<<AB3, 256, 0, stream>>>(xl3, xr3, csr_src, row_ptr, perm, a3, c3, outp);
}

// Round 12
// 259.577 us; speedup vs baseline: 1.0396x; 1.0396x over previous
//
#include <hip/hip_runtime.h>
#include <math.h>

#define NN 50000
#define NE 800000
#define SLOPE 0.2f
#define NEGX (-1e30f)
#define CH 4096
#define HB 128

typedef _Float16 h8 __attribute__((ext_vector_type(8)));
typedef _Float16 h2 __attribute__((ext_vector_type(2)));
typedef float f8 __attribute__((ext_vector_type(8)));
typedef float v4f __attribute__((ext_vector_type(4)));

__device__ __forceinline__ h8 hzero(){ h8 z = {0,0,0,0,0,0,0,0}; return z; }
__device__ __forceinline__ f8 fzero(){ f8 z = {0,0,0,0,0,0,0,0}; return z; }

// ---------------- fused weight pack (fp16 fragment order) + edge histogram ----
__device__ __forceinline__ void pack_one(const float* __restrict__ W,
                                         _Float16* __restrict__ Wp,
                                         int DO, int K, int NT, int t){
  int KC = K >> 5;
  if (t >= NT * KC * 64) return;
  int lane = t & 63;
  int rest = t >> 6;
  int c  = rest % KC;
  int nt = rest / KC;
  int col = nt * 16 + (lane & 15);
  int k0  = c * 32 + ((lane >> 4) << 3);
  _Float16 o[8];
#pragma unroll
  for (int j = 0; j < 8; j++){
    float v = (col < DO) ? W[(k0 + j) * DO + col] : 0.f;
    o[j] = (_Float16)v;
  }
  *(ulonglong2*)(Wp + (size_t)t * 8) = *(ulonglong2*)o;
}

// packs weights; histograms edges by dst bucket (LDS atomics only -> gbp
// partials, HB=128 hist blocks for latency hiding); zeroes cursor arrays;
// writes row_ptr[NN]=NE.
__global__ __launch_bounds__(256) void k_pack_hist(
    const float* W1l, const float* W1r, const float* W2l,
    const float* W2r, const float* W3l, const float* W3r,
    _Float16* p1l, _Float16* p1r, _Float16* p2l,
    _Float16* p2r, _Float16* p3l, _Float16* p3r,
    const int* __restrict__ ei, int* __restrict__ gbp,
    int* __restrict__ bcur, int* __restrict__ row_ptr){
  __shared__ int h[256];
  int b = blockIdx.x, t = threadIdx.x;
  if (b < 44){
    if      (b < 16) pack_one(W1l, p1l, 128, 256, 8, (b     ) * 256 + t);
    else if (b < 32) pack_one(W1r, p1r, 128, 256, 8, (b - 16) * 256 + t);
    else if (b < 36) pack_one(W2l, p2l,  64, 128, 4, (b - 32) * 256 + t);
    else if (b < 40) pack_one(W2r, p2r,  64, 128, 4, (b - 36) * 256 + t);
    else if (b < 42) pack_one(W3l, p3l,  40,  64, 3, (b - 40) * 256 + t);
    else             pack_one(W3r, p3r,  40,  64, 3, (b - 42) * 256 + t);
  } else {
    int hb = b - 44;                 // 0..HB-1, each owns NE/HB = 6250 edges
    if (hb == 0 && t == 0) row_ptr[NN] = NE;
    if (hb == 1){ bcur[t] = 0; bcur[256 + t] = 0; bcur[512 + t] = 0; }
    h[t] = 0;
    __syncthreads();
    int e0 = hb * (NE / HB);
    for (int i = t; i < NE / HB; i += 256)
      atomicAdd(&h[ei[NE + e0 + i] >> 8], 1);
    __syncthreads();
    gbp[hb * 256 + t] = h[t];        // non-atomic partials
  }
}

// ---------------- Direct-load MFMA dual GEMM body (layer 1) ------------------
__device__ __forceinline__ void gemm_body(
    int bb,
    const float* __restrict__ X,
    const _Float16* __restrict__ Wpl, const float* __restrict__ bl,
    const _Float16* __restrict__ Wpr, const float* __restrict__ br,
    _Float16* __restrict__ Yl, _Float16* __restrict__ Yr)
{
  constexpr int K = 256, DO = 128;
  constexpr int KC = K / 32;
  constexpr int NT = DO / 16;
  int lane = threadIdx.x & 63;
  int wv   = threadIdx.x >> 6;
  int row0 = (bb * 4 + wv) * 16;           // m-tile base
  int arow = lane & 15;
  int koff = lane >> 4;
  int lrow = row0 + arow;
  int crow = (lrow < NN) ? lrow : 0;       // clamp loads; stores masked

  h8 afrag[KC];
  const float* Xr = X + (size_t)crow * K + koff * 8;
#pragma unroll
  for (int c = 0; c < KC; c++){
    float4 v0 = *reinterpret_cast<const float4*>(Xr + c * 32);
    float4 v1 = *reinterpret_cast<const float4*>(Xr + c * 32 + 4);
    h8 a;
    a[0]=(_Float16)v0.x; a[1]=(_Float16)v0.y; a[2]=(_Float16)v0.z; a[3]=(_Float16)v0.w;
    a[4]=(_Float16)v1.x; a[5]=(_Float16)v1.y; a[6]=(_Float16)v1.z; a[7]=(_Float16)v1.w;
    afrag[c] = a;
  }

#pragma unroll
  for (int side = 0; side < 2; side++){
    const _Float16* Wp = side ? Wpr : Wpl;
    const float* bias = side ? br : bl;
    _Float16* Y = side ? Yr : Yl;
#pragma unroll
    for (int nt = 0; nt < NT; nt++){
      v4f acc = {0.f, 0.f, 0.f, 0.f};
#pragma unroll
      for (int c = 0; c < KC; c++){
        h8 b = *reinterpret_cast<const h8*>(Wp + (size_t)((nt * KC + c) * 64 + lane) * 8);
        acc = __builtin_amdgcn_mfma_f32_16x16x32_f16(afrag[c], b, acc, 0, 0, 0);
      }
      int col = nt * 16 + arow;            // C/D: col = lane&15
      if (col < DO){
        float bv = bias[col];
        int rbase = row0 + koff * 4;       // C/D: row = (lane>>4)*4 + reg
#pragma unroll
        for (int r = 0; r < 4; r++){
          int orow = rbase + r;
          if (orow < NN) Y[(size_t)orow * DO + col] = (_Float16)(acc[r] + bv);
        }
      }
    }
  }
}

#define GB ((NN + 63) / 64)             // 782 gemm1 blocks
#define SB ((NE + CH - 1) / CH)         // 196 scatter blocks

// ---------------- Fused dispatch: gemm1 (first, long pole) || bscatter -------
// blocks 0..GB-1     : layer-1 dual GEMM (independent of CSR chain)
// blocks GB..GB+SB-1 : edge scatter into dst buckets (self-scans gbp for
//                      bases; first scatter block publishes base[] for k_bcsr)
// CH=4096 keeps LDS at 18.4KB so the GEMM blocks get 8 blocks/CU.
__global__ __launch_bounds__(256, 4) void k_fused2(
    const int* __restrict__ ei, const int* __restrict__ gbp,
    int* __restrict__ bcur, int* __restrict__ base,
    unsigned* __restrict__ pk_out,
    const float* __restrict__ X,
    const _Float16* __restrict__ Wpl, const float* __restrict__ bl,
    const _Float16* __restrict__ Wpr, const float* __restrict__ br,
    _Float16* __restrict__ Yl, _Float16* __restrict__ Yr)
{
  __shared__ unsigned smem[CH + 512];
  int b = blockIdx.x, t = threadIdx.x;
  if (b < GB){
    gemm_body(b, X, Wpl, bl, Wpr, br, Yl, Yr);
  } else {
    int sb = b - GB;
    unsigned* pk = smem;
    int* h = (int*)(smem + CH);
    int* s = h + 256;
    // self-scan of gbp -> bucket base (exclusive)
    int v = 0;
#pragma unroll 8
    for (int i = 0; i < HB; i++) v += gbp[i * 256 + t];
    s[t] = v; __syncthreads();
    for (int off = 1; off < 256; off <<= 1){
      int a = (t >= off) ? s[t - off] : 0;
      __syncthreads(); s[t] += a; __syncthreads();
    }
    int ex = s[t] - v;
    if (sb == 0){
      base[t] = ex;
      if (t == 255) base[256] = NE;
    }
    h[t] = 0;
    __syncthreads();
    int e0 = sb * CH;
    int n = NE - e0; if (n > CH) n = CH;
    for (int i = t; i < n; i += 256){
      int e = e0 + i;
      int sN = ei[e], d = ei[NE + e];
      pk[i] = (unsigned)sN | ((unsigned)(d & 255) << 16) | ((unsigned)(d >> 8) << 24);
      atomicAdd(&h[d >> 8], 1);
    }
    __syncthreads();
    int c = h[t];
    if (c) h[t] = ex + atomicAdd(&bcur[t], c);
    __syncthreads();
    for (int i = t; i < n; i += 256){
      unsigned u = pk[i];
      int pos = atomicAdd(&h[u >> 24], 1);
      pk_out[pos] = u;
    }
  }
}

// per-bucket CSR finalize + per-node degree histogram (for degree sort)
__global__ __launch_bounds__(256) void k_bcsr(const unsigned* __restrict__ pk,
                                              const int* __restrict__ base,
                                              int* __restrict__ row_ptr,
                                              int* __restrict__ csr_src,
                                              int* __restrict__ dcnt){
  __shared__ int h[256], s[256];
  int t = threadIdx.x;
  int b = blockIdx.x;
  int lo = base[b], hi = base[b + 1];
  h[t] = 0;
  __syncthreads();
  for (int i = lo + t; i < hi; i += 256)
    atomicAdd(&h[(pk[i] >> 16) & 255], 1);
  __syncthreads();
  int v = h[t];
  s[t] = v; __syncthreads();
  for (int off = 1; off < 256; off <<= 1){
    int a = (t >= off) ? s[t - off] : 0;
    __syncthreads(); s[t] += a; __syncthreads();
  }
  int ex = lo + s[t] - v;
  int node = b * 256 + t;
  if (node < NN) row_ptr[node] = ex;
  h[t] = ex;
  // ---- degree histogram (reuse s[] as bins) ----
  s[t] = 0;
  __syncthreads();
  if (node < NN) atomicAdd(&s[v < 255 ? v : 255], 1);
  __syncthreads();
  if (s[t]) atomicAdd(&dcnt[t], s[t]);
  // ---- scatter csr ----
  for (int i = lo + t; i < hi; i += 256){
    unsigned u = pk[i];
    int pos = atomicAdd(&h[(u >> 16) & 255], 1);
    csr_src[pos] = (int)(u & 0xFFFFu);
  }
}

// degree-sort scatter; does its own (redundant per-block) scan of dcnt.
__global__ __launch_bounds__(256) void k_dscatter(const int* __restrict__ row_ptr,
                                                  const int* __restrict__ dcnt,
                                                  int* __restrict__ dcur,
                                                  int* __restrict__ perm){
  __shared__ int lh[256], sc[256];
  int t = threadIdx.x;
  int node = blockIdx.x * 256 + t;
  lh[t] = 0;
  int dv = dcnt[t];
  __syncthreads();
  int bin = -1;
  if (node < NN){
    int deg = row_ptr[node + 1] - row_ptr[node];
    bin = deg < 255 ? deg : 255;
    atomicAdd(&lh[bin], 1);
  }
  sc[t] = dv;
  __syncthreads();
  for (int off = 1; off < 256; off <<= 1){
    int a = (t >= off) ? sc[t - off] : 0;
    __syncthreads(); sc[t] += a; __syncthreads();
  }
  int gbase = sc[t] - dv;             // exclusive global base of bin t
  int c = lh[t];
  int bp = c ? (gbase + atomicAdd(&dcur[t], c)) : 0;
  __syncthreads();
  lh[t] = bp;
  __syncthreads();
  if (node < NN){
    int pos = atomicAdd(&lh[bin], 1);
    perm[pos] = node;
  }
}

// ---------------- agg helpers ----------------
// DPP-based cross-lane reduction: pure VALU (no ds_swizzle latency chain).
template<int CTRL>
__device__ __forceinline__ float dppmv(float v){
  int x = __builtin_amdgcn_update_dpp(0, __float_as_int(v), CTRL, 0xF, 0xF, true);
  return __int_as_float(x);
}

template<int LPG>
__device__ __forceinline__ float gsum(float v){
  v += dppmv<177>(v);                 // quad_perm [1,0,3,2]  (xor1)
  v += dppmv<78>(v);                  // quad_perm [2,3,0,1]  (xor2)
  if (LPG >= 8)  v += dppmv<0x141>(v);  // row_half_mirror (cross-quad)
  if (LPG == 16) v += dppmv<0x140>(v);  // row_mirror (cross-half)
  return v;
}
template<int LPG>
__device__ __forceinline__ void gsum2(float& a, float& b){
  a = gsum<LPG>(a);
  b = gsum<LPG>(b);
}
template<int LPG>
__device__ __forceinline__ void gsum4(float& a, float& b, float& c, float& d){
  a = gsum<LPG>(a);
  b = gsum<LPG>(b);
  c = gsum<LPG>(c);
  d = gsum<LPG>(d);
}
template<int LPG>
__device__ __forceinline__ float gmax(float v){
  v = fmaxf(v, dppmv<177>(v));
  v = fmaxf(v, dppmv<78>(v));
  if (LPG >= 8)  v = fmaxf(v, dppmv<0x141>(v));
  if (LPG == 16) v = fmaxf(v, dppmv<0x140>(v));
  return v;
}

__device__ __forceinline__ float edge_logit(h8 x, h8 xrv, h8 attv){
  h8 t = x + xrv;
  h8 l = __builtin_elementwise_max(t, t * (_Float16)SLOPE);
  const h2* lp = (const h2*)&l;
  const h2* ap = (const h2*)&attv;
  float d = __builtin_amdgcn_fdot2(lp[0], ap[0], 0.f, false);
  d = __builtin_amdgcn_fdot2(lp[1], ap[1], d, false);
  d = __builtin_amdgcn_fdot2(lp[2], ap[2], d, false);
  d = __builtin_amdgcn_fdot2(lp[3], ap[3], d, false);
  return d;
}

// weighted accumulate, element-wise fp16->f32 mixed FMA (v_fma_mix_f32).
__device__ __forceinline__ void fmix(f8& acc, h8 x, float w){
#pragma unroll
  for (int j = 0; j < 8; j++) acc[j] = fmaf((float)x[j], w, acc[j]);
}

// ---------------- Fused agg(layer l) + gemm(layer l+1) ----------------
template<int DO, int LPG, int DO2>
__global__ __launch_bounds__(256) void agg_gemm(
    const _Float16* __restrict__ xl, const _Float16* __restrict__ xr,
    const int* __restrict__ csr_src, const int* __restrict__ row_ptr,
    const int* __restrict__ perm,
    const float* __restrict__ att, const float* __restrict__ bias,
    const _Float16* __restrict__ Wpl2, const float* __restrict__ bl2,
    const _Float16* __restrict__ Wpr2, const float* __restrict__ br2,
    _Float16* __restrict__ Yl, _Float16* __restrict__ Yr)
{
  constexpr int G = 64 / LPG;
  constexpr int NPB = 4 * G;            // nodes per block
  constexpr int LK = DO + 8;            // padded LDS row stride (halves)
  constexpr int KC2 = DO / 32;
  constexpr int NT2 = (DO2 + 15) / 16;
  constexpr int MT = NPB / 16;          // m-tiles per block (1 or 2)
  __shared__ _Float16 hs[NPB * LK];
  __shared__ int nodeOf[NPB];

  int tid  = threadIdx.x;
  int lane = tid & 63;
  int wid  = tid >> 6;

  unsigned seg = (unsigned)(blockIdx.x * 1021u) % gridDim.x;  // coprime interleave
  if (tid < NPB){
    int idx = seg * NPB + tid;
    nodeOf[tid] = (idx < NN) ? perm[idx] : NN;
  }
  __syncthreads();

  int g = lane / LPG, p = lane % LPG;
  int nodeLocal = wid * G + g;
  int node = nodeOf[nodeLocal];
  int cbase = p * 8;
  bool nvalid = node < NN;
  int nodeC = nvalid ? node : 0;

  // ---- agg phase ----
  h8 attv, xrv, xlv;
  {
    float4 a0 = *reinterpret_cast<const float4*>(att + cbase);
    float4 a1 = *reinterpret_cast<const float4*>(att + cbase + 4);
    attv[0]=(_Float16)a0.x; attv[1]=(_Float16)a0.y; attv[2]=(_Float16)a0.z; attv[3]=(_Float16)a0.w;
    attv[4]=(_Float16)a1.x; attv[5]=(_Float16)a1.y; attv[6]=(_Float16)a1.z; attv[7]=(_Float16)a1.w;
    xrv = *reinterpret_cast<const h8*>(xr + nodeC * DO + cbase);
    xlv = *reinterpret_cast<const h8*>(xl + nodeC * DO + cbase);
  }
  float s = gsum<LPG>(edge_logit(xlv, xrv, attv));
  float wS = __expf(s);
  float denA = wS, denB = 0.f;
  f8 accA = fzero(), accB = fzero();
  fmix(accA, xlv, wS);

  int e0 = row_ptr[nodeC];
  int e1 = nvalid ? row_ptr[nodeC + 1] : e0;
  int e = e0;
  for (; e + 3 < e1; e += 4){
    int s0 = csr_src[e],     s1 = csr_src[e + 1];
    int s2 = csr_src[e + 2], s3 = csr_src[e + 3];
    h8 x0 = *reinterpret_cast<const h8*>(xl + s0 * DO + cbase);
    h8 x1 = *reinterpret_cast<const h8*>(xl + s1 * DO + cbase);
    h8 x2 = *reinterpret_cast<const h8*>(xl + s2 * DO + cbase);
    h8 x3 = *reinterpret_cast<const h8*>(xl + s3 * DO + cbase);
    float p0 = edge_logit(x0, xrv, attv);
    float p1 = edge_logit(x1, xrv, attv);
    float p2 = edge_logit(x2, xrv, attv);
    float p3 = edge_logit(x3, xrv, attv);
    gsum4<LPG>(p0, p1, p2, p3);
    float w0 = __expf(p0), w1 = __expf(p1);
    float w2 = __expf(p2), w3 = __expf(p3);
    denA += w0 + w2; denB += w1 + w3;
    fmix(accA, x0, w0);
    fmix(accB, x1, w1);
    fmix(accA, x2, w2);
    fmix(accB, x3, w3);
  }
  for (; e + 1 < e1; e += 2){
    int sA = csr_src[e], sB = csr_src[e + 1];
    h8 xA = *reinterpret_cast<const h8*>(xl + sA * DO + cbase);
    h8 xB = *reinterpret_cast<const h8*>(xl + sB * DO + cbase);
    float pA = edge_logit(xA, xrv, attv);
    float pB = edge_logit(xB, xrv, attv);
    gsum2<LPG>(pA, pB);
    float wA = __expf(pA), wB = __expf(pB);
    denA += wA; denB += wB;
    fmix(accA, xA, wA);
    fmix(accB, xB, wB);
  }
  if (e < e1){
    int sA = csr_src[e];
    h8 xA = *reinterpret_cast<const h8*>(xl + sA * DO + cbase);
    float pA = gsum<LPG>(edge_logit(xA, xrv, attv));
    float w = __expf(pA);
    denA += w;
    fmix(accA, xA, w);
  }

  {
    float inv = 1.0f / (denA + denB);
    f8 sum = (accA + accB) * inv;
    float4 b0 = *reinterpret_cast<const float4*>(bias + cbase);
    float4 b1 = *reinterpret_cast<const float4*>(bias + cbase + 4);
    f8 bv = {b0.x, b0.y, b0.z, b0.w, b1.x, b1.y, b1.z, b1.w};
    sum += bv;
    sum = __builtin_elementwise_max(sum, fzero());
    *reinterpret_cast<h8*>(&hs[nodeLocal * LK + cbase]) = __builtin_convertvector(sum, h8);
  }
  __syncthreads();

  // ---- gemm phase: next layer, A from LDS, B from packed W (L2) ----
  int arow = lane & 15;
  int koff = lane >> 4;
  int mt = (MT == 1) ? 0 : (wid >> 1);
  h8 afrag[KC2];
#pragma unroll
  for (int c = 0; c < KC2; c++)
    afrag[c] = *reinterpret_cast<const h8*>(&hs[(mt * 16 + arow) * LK + koff * 8 + c * 32]);

  int side = wid & 1;
  const _Float16* Wp = side ? Wpr2 : Wpl2;
  const float* bias2 = side ? br2 : bl2;
  _Float16* Y = side ? Yr : Yl;
  int nt_begin = (MT == 1) ? (wid >> 1) * (NT2 / 2) : 0;
  int nt_end   = (MT == 1) ? nt_begin + NT2 / 2 : NT2;
  for (int nt = nt_begin; nt < nt_end; nt++){
    v4f acc = {0.f, 0.f, 0.f, 0.f};
#pragma unroll
    for (int c = 0; c < KC2; c++){
      h8 b = *reinterpret_cast<const h8*>(Wp + (size_t)((nt * KC2 + c) * 64 + lane) * 8);
      acc = __builtin_amdgcn_mfma_f32_16x16x32_f16(afrag[c], b, acc, 0, 0, 0);
    }
    int col = nt * 16 + arow;
    if (col < DO2){
      float bv = bias2[col];
      int lrbase = mt * 16 + koff * 4;   // C/D: row = (lane>>4)*4 + reg
#pragma unroll
      for (int r = 0; r < 4; r++){
        int orow = nodeOf[lrbase + r];
        if (orow < NN) Y[(size_t)orow * DO2 + col] = (_Float16)(acc[r] + bv);
      }
    }
  }
}

// ---------------- Final GATv2 aggregate + bias + log_softmax ----------------
template<int DO, int LPG>
__global__ __launch_bounds__(256) void gat_agg_out(
    const _Float16* __restrict__ xl, const _Float16* __restrict__ xr,
    const int* __restrict__ csr_src, const int* __restrict__ row_ptr,
    const int* __restrict__ perm,
    const float* __restrict__ att, const float* __restrict__ bias,
    float* __restrict__ out)
{
  constexpr int G = 64 / LPG;
  constexpr int NPB = 4 * G;
  __shared__ int nodeOf[NPB];
  int tid  = threadIdx.x;
  int lane = tid & 63;
  int wid  = tid >> 6;

  unsigned seg = (unsigned)(blockIdx.x * 1021u) % gridDim.x;
  if (tid < NPB){
    int idx = seg * NPB + tid;
    nodeOf[tid] = (idx < NN) ? perm[idx] : NN;
  }
  __syncthreads();

  int g = lane / LPG;
  int p = lane % LPG;
  int node = nodeOf[wid * G + g];
  bool nvalid = node < NN;
  int nodeC = nvalid ? node : 0;
  int cbase = p * 8;
  bool ok = (cbase < DO);

  h8 attv = hzero(), xrv = hzero(), xlv = hzero();
  if (ok){
    float4 a0 = *reinterpret_cast<const float4*>(att + cbase);
    float4 a1 = *reinterpret_cast<const float4*>(att + cbase + 4);
    attv[0]=(_Float16)a0.x; attv[1]=(_Float16)a0.y; attv[2]=(_Float16)a0.z; attv[3]=(_Float16)a0.w;
    attv[4]=(_Float16)a1.x; attv[5]=(_Float16)a1.y; attv[6]=(_Float16)a1.z; attv[7]=(_Float16)a1.w;
    xrv = *reinterpret_cast<const h8*>(xr + nodeC * DO + cbase);
    xlv = *reinterpret_cast<const h8*>(xl + nodeC * DO + cbase);
  }

  float s = gsum<LPG>(edge_logit(xlv, xrv, attv));
  float wS = __expf(s);
  float denA = wS, denB = 0.f;
  f8 accA = fzero(), accB = fzero();
  fmix(accA, xlv, wS);

  int e0 = row_ptr[nodeC];
  int e1 = nvalid ? row_ptr[nodeC + 1] : e0;
  int e = e0;
  for (; e + 3 < e1; e += 4){
    int s0 = csr_src[e],     s1 = csr_src[e + 1];
    int s2 = csr_src[e + 2], s3 = csr_src[e + 3];
    h8 x0 = ok ? *reinterpret_cast<const h8*>(xl + s0 * DO + cbase) : hzero();
    h8 x1 = ok ? *reinterpret_cast<const h8*>(xl + s1 * DO + cbase) : hzero();
    h8 x2 = ok ? *reinterpret_cast<const h8*>(xl + s2 * DO + cbase) : hzero();
    h8 x3 = ok ? *reinterpret_cast<const h8*>(xl + s3 * DO + cbase) : hzero();
    float p0 = edge_logit(x0, xrv, attv);
    float p1 = edge_logit(x1, xrv, attv);
    float p2 = edge_logit(x2, xrv, attv);
    float p3 = edge_logit(x3, xrv, attv);
    gsum4<LPG>(p0, p1, p2, p3);
    float w0 = __expf(p0), w1 = __expf(p1);
    float w2 = __expf(p2), w3 = __expf(p3);
    denA += w0 + w2; denB += w1 + w3;
    fmix(accA, x0, w0);
    fmix(accB, x1, w1);
    fmix(accA, x2, w2);
    fmix(accB, x3, w3);
  }
  for (; e + 1 < e1; e += 2){
    int sA = csr_src[e], sB = csr_src[e + 1];
    h8 xA = ok ? *reinterpret_cast<const h8*>(xl + sA * DO + cbase) : hzero();
    h8 xB = ok ? *reinterpret_cast<const h8*>(xl + sB * DO + cbase) : hzero();
    float pA = edge_logit(xA, xrv, attv);
    float pB = edge_logit(xB, xrv, attv);
    gsum2<LPG>(pA, pB);
    float wA = __expf(pA), wB = __expf(pB);
    denA += wA; denB += wB;
    fmix(accA, xA, wA);
    fmix(accB, xB, wB);
  }
  if (e < e1){
    int sA = csr_src[e];
    h8 xA = ok ? *reinterpret_cast<const h8*>(xl + sA * DO + cbase) : hzero();
    float pA = gsum<LPG>(edge_logit(xA, xrv, attv));
    float w = __expf(pA);
    denA += w;
    fmix(accA, xA, w);
  }

  float inv = 1.0f / (denA + denB);
  f8 sumv = (accA + accB) * inv;
  float v[8]; float lmax = NEGX;
#pragma unroll
  for (int j = 0; j < 8; j++){
    v[j] = ok ? (sumv[j] + bias[cbase + j]) : NEGX;
    lmax = fmaxf(lmax, v[j]);
  }
  lmax = gmax<LPG>(lmax);
  float lsum = 0.f;
#pragma unroll
  for (int j = 0; j < 8; j++) lsum += __expf(v[j] - lmax);   // idle lanes: exp(NEGX)=0
  lsum = gsum<LPG>(lsum);
  if (ok && nvalid){
    float lg = lmax + __logf(lsum);
    float* op = (float*)out + node * DO + cbase;
    float4 o0, o1;
    o0.x = v[0] - lg; o0.y = v[1] - lg; o0.z = v[2] - lg; o0.w = v[3] - lg;
    o1.x = v[4] - lg; o1.y = v[5] - lg; o1.z = v[6] - lg; o1.w = v[7] - lg;
    *reinterpret_cast<float4*>(op) = o0;
    *reinterpret_cast<float4*>(op + 4) = o1;
  }
}

extern "C" void kernel_launch(void* const* d_in, const int* in_sizes, int n_in,
                              void* d_out, int out_size, void* d_ws, size_t ws_size,
                              hipStream_t stream) {
  const float* x   = (const float*)d_in[0];
  const int*   ei  = (const int*)d_in[1];
  const float* W1l = (const float*)d_in[2];  const float* W1r = (const float*)d_in[3];
  const float* b1l = (const float*)d_in[4];  const float* b1r = (const float*)d_in[5];
  const float* a1  = (const float*)d_in[6];  const float* c1  = (const float*)d_in[7];
  const float* W2l = (const float*)d_in[8];  const float* W2r = (const float*)d_in[9];
  const float* b2l = (const float*)d_in[10]; const float* b2r = (const float*)d_in[11];
  const float* a2  = (const float*)d_in[12]; const float* c2  = (const float*)d_in[13];
  const float* W3l = (const float*)d_in[14]; const float* W3r = (const float*)d_in[15];
  const float* b3l = (const float*)d_in[16]; const float* b3r = (const float*)d_in[17];
  const float* a3  = (const float*)d_in[18]; const float* c3  = (const float*)d_in[19];
  float* outp = (float*)d_out;

  // workspace layout (16B-aligned segments)
  _Float16* xl1 = (_Float16*)d_ws;        // 50000*128
  _Float16* xr1 = xl1 + 6400000;
  _Float16* xl2 = xr1 + 6400000;          // 50000*64
  _Float16* xr2 = xl2 + 3200000;
  _Float16* xl3 = xr2 + 3200000;          // 50000*40
  _Float16* xr3 = xl3 + 2000000;
  _Float16* wp1l = xr3 + 2000000;         // packed weights (fp16)
  _Float16* wp1r = wp1l + 32768;
  _Float16* wp2l = wp1r + 32768;
  _Float16* wp2r = wp2l + 8192;
  _Float16* wp3l = wp2r + 8192;
  _Float16* wp3r = wp3l + 3072;
  unsigned* pk   = (unsigned*)(wp3r + 3072);   // 800000
  int* csr_src   = (int*)(pk + NE);            // 800000
  int* row_ptr   = csr_src + NE;               // 50001
  int* gbp       = row_ptr + 50001;            // HB*256 partial hist
  int* base      = gbp + HB * 256;             // 257
  // cursor block (zeroed by k_pack_hist, contiguous): bcur(256) dcnt(256) dcur(256)
  int* bcur      = base + 257;
  int* dcnt      = bcur + 256;
  int* dcur      = dcnt + 256;
  int* perm      = dcur + 256;                 // 50000 degree-sorted node ids

  const int FB1 = (NN + 15) / 16;         // fused agg1+gemm2: 16 nodes/block
  const int FB2 = (NN + 31) / 32;         // fused agg2+gemm3: 32 nodes/block
  const int AB3 = (NN + 31) / 32;         // agg3: 32 nodes/block (LPG=8)
  const int F2  = GB + SB;                // fused gemm+scatter grid (978)

  // pack weights + bucket histogram + cursor zeroing + row_ptr[NN]
  k_pack_hist<<<44 + HB, 256, 0, stream>>>(W1l, W1r, W2l, W2r, W3l, W3r,
                                           wp1l, wp1r, wp2l, wp2r, wp3l, wp3r,
                                           ei, gbp, bcur, row_ptr);

  // fused: layer-1 GEMM (blocks first) || edge scatter (self-scan, publishes base)
  k_fused2<<<F2, 256, 0, stream>>>(ei, gbp, bcur, base, pk,
                                   x, wp1l, b1l, wp1r, b1r, xl1, xr1);

  // CSR finalize + degree histogram
  k_bcsr<<<196, 256, 0, stream>>>(pk, base, row_ptr, csr_src, dcnt);

  // degree-sort perm
  k_dscatter<<<196, 256, 0, stream>>>(row_ptr, dcnt, dcur, perm);

  // fused: agg layer1 (relu) + gemm layer2 -> xl2, xr2
  agg_gemm<128,16,64><<<FB1, 256, 0, stream>>>(xl1, xr1, csr_src, row_ptr, perm,
                                               a1, c1, wp2l, b2l, wp2r, b2r, xl2, xr2);

  // fused: agg layer2 (relu) + gemm layer3 -> xl3, xr3
  agg_gemm<64,8,40><<<FB2, 256, 0, stream>>>(xl2, xr2, csr_src, row_ptr, perm,
                                             a2, c2, wp3l, b3l, wp3r, b3r, xl3, xr3);

  // final: agg layer3 + bias + log_softmax -> out
  gat_agg_out<40,8><<<AB3, 256, 0, stream>>>(xl3, xr3, csr_src, row_ptr, perm, a3, c3, outp);
}